// Round 17
// baseline (586.879 us; speedup 1.0000x reference)
//
#include <hip/hip_runtime.h>
#include <math.h>

// Problem constants
constexpr int N_  = 50000;
constexpr int E_  = 800000;
constexpr int H_  = 8;
constexpr int C_  = 16;
constexpr int HC_ = 128;
constexpr int ED_ = 16;        // E_DIM
constexpr int FF_ = 512;
constexpr int NT_ = 3125;      // row tiles of 16 (50000 = 16*3125 exact)
constexpr float NEG_ = 0.2f;
constexpr float EPS_ = 1e-5f;
constexpr float LAMBDA_INIT_ = 0.8f;
constexpr float LOG2E_ = 1.4426950408889634f;

typedef __attribute__((ext_vector_type(8))) short bf16x8;
typedef __attribute__((ext_vector_type(4))) float f32x4;
typedef __fp16 half2v __attribute__((ext_vector_type(2)));

__device__ __forceinline__ float gelu_exact(float v) {
    return 0.5f * v * (1.0f + erff(v * 0.70710678118654752440f));
}
__device__ __forceinline__ ushort f2bf(float f) {  // RNE f32 -> bf16
    uint u = __float_as_uint(f);
    return (ushort)((u + 0x7FFFu + ((u >> 16) & 1u)) >> 16);
}
__device__ __forceinline__ ushort f2h(float f) {   // f32 -> f16 bits (RNE)
    __fp16 h = (__fp16)f;
    return *(ushort*)&h;
}
__device__ __forceinline__ uint pkh2(float a, float b) {  // 2xf32 -> packed f16x2
    half2v h = __builtin_amdgcn_cvt_pkrtz(a, b);
    return *(uint*)&h;
}
__device__ __forceinline__ void uph2(uint u, float& a, float& b) {
    half2v h = *(half2v*)&u;
    a = (float)h.x; b = (float)h.y;
}

// ---------------- consolidated conversion kernel (+ degree histogram) ----------------
constexpr int WL12_ = 288 * 128;
constexpr int WO_   = 128 * 128;
constexpr int WF1_  = 512 * 128;
constexpr int WF2_  = 128 * 512;
constexpr int CVT_TOTAL_ = WL12_ + WO_ + WF1_ + WF2_ + 128 + 8 + E_;

__device__ void wconv(const float* __restrict__ W, ushort* __restrict__ Wt, int t, int K, int N) {
    int col = t / K, k = t - col * K;
    Wt[t] = f2bf(W[(size_t)k * N + col]);
}
__device__ void wconv_h(const float* __restrict__ W, ushort* __restrict__ Wt, int t, int K, int N) {
    int col = t / K, k = t - col * K;
    Wt[t] = f2h(W[(size_t)k * N + col]);
}

__global__ __launch_bounds__(256) void k_cvt(
        const float* __restrict__ Wl1, const float* __restrict__ al1w, const float* __restrict__ ar1w,
        const float* __restrict__ Wl2, const float* __restrict__ al2w, const float* __restrict__ ar2w,
        const float* __restrict__ Wout, const float* __restrict__ Wff1, const float* __restrict__ Wff2,
        const float* __restrict__ We1, const float* __restrict__ ae1,
        const float* __restrict__ We2, const float* __restrict__ ae2,
        const float* __restrict__ lq1, const float* __restrict__ lk1,
        const float* __restrict__ lq2, const float* __restrict__ lk2,
        const int* __restrict__ dst0,
        ushort* __restrict__ wl12t,
        ushort* __restrict__ woutt, ushort* __restrict__ wff1t, ushort* __restrict__ wff2t,
        float2* __restrict__ wc, float* __restrict__ lam,
        int* __restrict__ deg, int* __restrict__ rank) {
    int g = blockIdx.x * blockDim.x + threadIdx.x;
    if (g < WL12_) {
        int col = g >> 7, k = g & 127;
        const float* W = (col < 144) ? Wl1 : Wl2;
        const float* alw = (col < 144) ? al1w : al2w;
        const float* arw = (col < 144) ? ar1w : ar2w;
        int c = (col < 144) ? col : col - 144;
        float v;
        if (c < 128) {
            v = W[(size_t)k * HC_ + c];
        } else if (c < 136) {
            int h = c - 128; v = 0.f;
#pragma unroll
            for (int cc = 0; cc < 16; ++cc) v = fmaf(W[(size_t)k * HC_ + h * 16 + cc], alw[h * 16 + cc], v);
        } else {
            int h = c - 136; v = 0.f;
#pragma unroll
            for (int cc = 0; cc < 16; ++cc) v = fmaf(W[(size_t)k * HC_ + h * 16 + cc], arw[h * 16 + cc], v);
        }
        wl12t[g] = f2bf(v);
        return;
    }
    g -= WL12_;
    if (g < WO_) { wconv(Wout, woutt, g, 128, 128); return; }
    g -= WO_;
    if (g < WF1_) { wconv(Wff1, wff1t, g, 128, 512); return; }
    g -= WF1_;
    if (g < WF2_) { wconv_h(Wff2, wff2t, g, 512, 128); return; }
    g -= WF2_;
    if (g < 128) {
        int k = g >> 3, h = g & 7;
        float s1 = 0.f, s2 = 0.f;
#pragma unroll
        for (int c = 0; c < 16; ++c) {
            s1 = fmaf(We1[k * HC_ + h * 16 + c], ae1[h * 16 + c], s1);
            s2 = fmaf(We2[k * HC_ + h * 16 + c], ae2[h * 16 + c], s2);
        }
        wc[g] = make_float2(s1, s2);
        return;
    }
    g -= 128;
    if (g < 8) {
        float d1 = 0.f, d2 = 0.f;
#pragma unroll
        for (int k = 0; k < 16; ++k) {
            d1 = fmaf(lq1[g * 16 + k], lk1[g * 16 + k], d1);
            d2 = fmaf(lq2[g * 16 + k], lk2[g * 16 + k], d2);
        }
        lam[g] = __expf(d1) - __expf(d2) + LAMBDA_INIT_;
        return;
    }
    g -= 8;
    if (g < E_) {
        rank[g] = atomicAdd(&deg[dst0[g]], 1);
    }
}

// ---------------- exclusive scan of deg -> offsets; degree-bucket offsets ----------------
__global__ __launch_bounds__(1024) void k_scan(const int* __restrict__ deg,
                                               int* __restrict__ offs,
                                               int* __restrict__ bktcur) {
    __shared__ int part[1024];
    __shared__ int hist[64];
    int t = threadIdx.x;
    const int CH = (N_ + 1023) / 1024;  // 49
    int b = t * CH;
    int e = min(N_, b + CH);
    if (t < 64) hist[t] = 0;
    int sum = 0;
    for (int i = b; i < e; ++i) sum += deg[i];
    part[t] = sum;
    __syncthreads();
    for (int off = 1; off < 1024; off <<= 1) {
        int v = (t >= off) ? part[t - off] : 0;
        __syncthreads();
        part[t] += v;
        __syncthreads();
    }
    int run = (t == 0) ? 0 : part[t - 1];
    for (int i = b; i < e; ++i) {
        offs[i] = run;
        run += deg[i];
        atomicAdd(&hist[min(deg[i], 63)], 1);
    }
    if (t == 1023) offs[N_] = run;  // == E_
    __syncthreads();
    if (t == 0) {
        int r2 = 0;
        for (int d = 0; d < 64; ++d) {
            bktcur[d] = r2;
            r2 += hist[d];
        }
    }
}

// ---------------- node permutation by degree bucket (load balance for k_agg) ----------------
__global__ __launch_bounds__(256) void k_perm(const int* __restrict__ deg,
                                              int* __restrict__ bktcur,
                                              int* __restrict__ perm) {
    int i = blockIdx.x * blockDim.x + threadIdx.x;
    if (i >= N_) return;
    int d = min(deg[i], 63);
    int pos = atomicAdd(&bktcur[d], 1);
    perm[pos] = i;
}

// ---------------- CSR fill: 12B/edge scatter (src 4B + (dst,eid) 8B) ----------------
__global__ __launch_bounds__(256) void k_fill(const int* __restrict__ src0,
                                              const int* __restrict__ dst0,
                                              const int* __restrict__ offs,
                                              const int* __restrict__ rank,
                                              int* __restrict__ csr_src,
                                              int2* __restrict__ csr_de) {
    int e = blockIdx.x * blockDim.x + threadIdx.x;
    if (e >= E_) return;
    int d = dst0[e];
    int p = offs[d] + rank[e];
    csr_src[p] = src0[e];
    csr_de[p] = make_int2(d, e);
}

// ---------------- per-edge record builder, CSR order (sequential writes) ----------------
__global__ __launch_bounds__(256) void k_et(const float* __restrict__ eattr,
                                            const float2* __restrict__ all_,
                                            const float2* __restrict__ arr_,
                                            const float2* __restrict__ wc,
                                            const int* __restrict__ csr_src,
                                            const int2* __restrict__ csr_de,
                                            uint* __restrict__ rec) {
    __shared__ float2 wcs[128];
    int t = threadIdx.x;
    if (t < 128) wcs[t] = wc[t];
    __syncthreads();
    int p = blockIdx.x * blockDim.x + t;
    if (p >= E_) return;
    int2 de = csr_de[p];
    int dst = de.x, eid = de.y;
    int src = csr_src[p];
    const float* ea = eattr + (size_t)eid * ED_;
    float eav[16];
    {
        float4 q0 = *(const float4*)(ea + 0);
        float4 q1 = *(const float4*)(ea + 4);
        float4 q2 = *(const float4*)(ea + 8);
        float4 q3 = *(const float4*)(ea + 12);
        eav[0] = q0.x; eav[1] = q0.y; eav[2] = q0.z; eav[3] = q0.w;
        eav[4] = q1.x; eav[5] = q1.y; eav[6] = q1.z; eav[7] = q1.w;
        eav[8] = q2.x; eav[9] = q2.y; eav[10] = q2.z; eav[11] = q2.w;
        eav[12] = q3.x; eav[13] = q3.y; eav[14] = q3.z; eav[15] = q3.w;
    }
    const float2* alp = all_ + (size_t)dst * 8;
    const float2* arp = arr_ + (size_t)src * 8;
    uint ra[8], re[8];
#pragma unroll
    for (int h = 0; h < 8; ++h) {
        float t1 = 0.f, t2 = 0.f;
#pragma unroll
        for (int k = 0; k < 16; ++k) {
            float2 w = wcs[k * 8 + h];
            t1 = fmaf(eav[k], w.x, t1);
            t2 = fmaf(eav[k], w.y, t2);
        }
        float2 al = alp[h], ar = arp[h];
        float a1 = al.x + ar.x + t1;
        a1 = ((a1 >= 0.f) ? a1 : NEG_ * a1) * LOG2E_;
        float a2 = al.y + ar.y + t2;
        a2 = ((a2 >= 0.f) ? a2 : NEG_ * a2) * LOG2E_;
        ra[h] = pkh2(exp2f(a1), exp2f(a2));   // store p directly (max-free softmax)
    }
#pragma unroll
    for (int i = 0; i < 8; ++i) re[i] = pkh2(eav[2 * i], eav[2 * i + 1]);
    uint4* rp = (uint4*)(rec + (size_t)p * 16);
    rp[0] = make_uint4(ra[0], ra[1], ra[2], ra[3]);
    rp[1] = make_uint4(ra[4], ra[5], ra[6], ra[7]);
    rp[2] = make_uint4(re[0], re[1], re[2], re[3]);
    rp[3] = make_uint4(re[4], re[5], re[6], re[7]);
}

// ---------------- fused dual attention + diff combine + rmsnorm ----------------
// Degree-bucketed node order (perm) + batch-8 gathers with pipelined csr_src.
__global__ __launch_bounds__(256) void k_agg(const ushort* __restrict__ x12,
                                             const float2* __restrict__ all_,
                                             const float2* __restrict__ arr_,
                                             const uint* __restrict__ rec,
                                             const float2* __restrict__ wcg,
                                             const float* __restrict__ We1, const float* __restrict__ We2,
                                             const float* __restrict__ lam, const float* __restrict__ rms_attn,
                                             const int* __restrict__ offs, const int* __restrict__ csr_src,
                                             const int* __restrict__ perm,
                                             ushort* __restrict__ attn_out) {
    int slot = (int)((blockIdx.x * blockDim.x + threadIdx.x) >> 6);
    if (slot >= N_) return;
    int wid = perm[slot];
    int lane = threadIdx.x & 63;
    int h = lane >> 3;
    int cp = lane & 7;
    int e0 = h * C_ + cp * 2;
    int hbase = lane & 56;

    int s = offs[wid], eend = offs[wid + 1];
    int deg = eend - s;

    float s1 = 0.f, s2 = 0.f;
    float ax1x = 0.f, ax1y = 0.f, ax2x = 0.f, ax2y = 0.f;
    float ws1x = 0.f, ws1y = 0.f, ws2x = 0.f, ws2y = 0.f;
    float esx = 0.f, esy = 0.f;

    auto accum = [&](uint ua, uint ue, uint2 ux) {
        float p1, p2, eax, eay, x1a, x2a, x1b, x2b;
        uph2(ua, p1, p2);
        uph2(ue, eax, eay);
        uph2(ux.x, x1a, x2a);
        uph2(ux.y, x1b, x2b);
        s1 += p1; s2 += p2;
        ax1x = fmaf(p1, x1a, ax1x); ax1y = fmaf(p1, x1b, ax1y);
        ax2x = fmaf(p2, x2a, ax2x); ax2y = fmaf(p2, x2b, ax2y);
        ws1x = fmaf(p1, eax, ws1x); ws1y = fmaf(p1, eay, ws1y);
        ws2x = fmaf(p2, eax, ws2x); ws2y = fmaf(p2, eay, ws2y);
        esx += eax; esy += eay;
    };

    int nb = deg >> 3;           // full batches of 8
    int srcv[8];
    if (nb > 0) {
#pragma unroll
        for (int q = 0; q < 8; ++q) srcv[q] = csr_src[s + q];
    }
    for (int b = 0; b < nb; ++b) {
        int jb = s + b * 8;
        uint uav[8], uev[8];
        uint2 uxv[8];
#pragma unroll
        for (int q = 0; q < 8; ++q) {
            const uint* r = rec + (size_t)(jb + q) * 16;
            uav[q] = r[h];
            uev[q] = r[8 + cp];
            uxv[q] = *(const uint2*)(x12 + (size_t)srcv[q] * 256 + e0 * 2);
        }
        int srcn[8];
        if (b + 1 < nb) {
#pragma unroll
            for (int q = 0; q < 8; ++q) srcn[q] = csr_src[jb + 8 + q];
        }
#pragma unroll
        for (int q = 0; q < 8; ++q) accum(uav[q], uev[q], uxv[q]);
#pragma unroll
        for (int q = 0; q < 8; ++q) srcv[q] = srcn[q];
    }
    for (int j = s + nb * 8; j < eend; ++j) {
        int src = csr_src[j];
        const uint* r = rec + (size_t)j * 16;
        uint ua = r[h];
        uint ue = r[8 + cp];
        uint2 ux = *(const uint2*)(x12 + (size_t)src * 256 + e0 * 2);
        accum(ua, ue, ux);
    }

    // ---- self-loop: ea_self = mean of incoming ea ----
    float invdeg = 1.0f / (float)max(deg, 1);
    float esmx = esx * invdeg, esmy = esy * invdeg;

    float2 w0 = wcg[(2 * cp) * 8 + h];
    float2 w1 = wcg[(2 * cp + 1) * 8 + h];
    float tp1 = esmx * w0.x + esmy * w1.x;
    float tp2 = esmx * w0.y + esmy * w1.y;
    tp1 += __shfl_xor(tp1, 1); tp1 += __shfl_xor(tp1, 2); tp1 += __shfl_xor(tp1, 4);
    tp2 += __shfl_xor(tp2, 1); tp2 += __shfl_xor(tp2, 2); tp2 += __shfl_xor(tp2, 4);

    float2 alv = all_[(size_t)wid * 8 + h];
    float2 arv = arr_[(size_t)wid * 8 + h];
    float aS1 = alv.x + arv.x + tp1;
    aS1 = ((aS1 >= 0.f) ? aS1 : NEG_ * aS1) * LOG2E_;
    float aS2 = alv.y + arv.y + tp2;
    aS2 = ((aS2 >= 0.f) ? aS2 : NEG_ * aS2) * LOG2E_;
    float pS1 = exp2f(aS1), pS2 = exp2f(aS2);
    {
        uint2 ux = *(const uint2*)(x12 + (size_t)wid * 256 + e0 * 2);
        float x1a, x2a, x1b, x2b;
        uph2(ux.x, x1a, x2a);
        uph2(ux.y, x1b, x2b);
        s1 += pS1; s2 += pS2;
        ax1x = fmaf(pS1, x1a, ax1x); ax1y = fmaf(pS1, x1b, ax1y);
        ax2x = fmaf(pS2, x2a, ax2x); ax2y = fmaf(pS2, x2b, ax2y);
        ws1x = fmaf(pS1, esmx, ws1x); ws1y = fmaf(pS1, esmy, ws1y);
        ws2x = fmaf(pS2, esmx, ws2x); ws2y = fmaf(pS2, esmy, ws2y);
    }

    // ---- final: out = (ax + ws @ We) / s ----
    float o1x = ax1x, o1y = ax1y, o2x = ax2x, o2y = ax2y;
#pragma unroll
    for (int kp = 0; kp < 8; ++kp) {
        float wa1 = __shfl(ws1x, hbase + kp), wb1 = __shfl(ws1y, hbase + kp);
        float wa2 = __shfl(ws2x, hbase + kp), wb2 = __shfl(ws2y, hbase + kp);
        float2 a0 = *(const float2*)(We1 + (2 * kp) * HC_ + e0);
        float2 a1 = *(const float2*)(We1 + (2 * kp + 1) * HC_ + e0);
        float2 b0 = *(const float2*)(We2 + (2 * kp) * HC_ + e0);
        float2 b1 = *(const float2*)(We2 + (2 * kp + 1) * HC_ + e0);
        o1x = fmaf(wa1, a0.x, o1x); o1x = fmaf(wb1, a1.x, o1x);
        o1y = fmaf(wa1, a0.y, o1y); o1y = fmaf(wb1, a1.y, o1y);
        o2x = fmaf(wa2, b0.x, o2x); o2x = fmaf(wb2, b1.x, o2x);
        o2y = fmaf(wa2, b0.y, o2y); o2y = fmaf(wb2, b1.y, o2y);
    }
    float inv1 = 1.0f / s1, inv2 = 1.0f / s2;
    o1x *= inv1; o1y *= inv1; o2x *= inv2; o2y *= inv2;

    float lamh = lam[h];
    float v0 = o1x - lamh * o2x;
    float v1 = o1y - lamh * o2y;

    float ss = v0 * v0 + v1 * v1;
#pragma unroll
    for (int mk = 1; mk < 64; mk <<= 1) ss += __shfl_xor(ss, mk);
    float rn = rsqrtf(ss * (1.0f / 128.0f) + EPS_);
    float g0 = rms_attn[e0] * (1.0f - LAMBDA_INIT_);
    float g1 = rms_attn[e0 + 1] * (1.0f - LAMBDA_INIT_);
    ushort2 o;
    o.x = f2bf(v0 * rn * g0);
    o.y = f2bf(v1 * rn * g1);
    *(ushort2*)(attn_out + (size_t)wid * HC_ + e0) = o;
}

// ---------------- persistent node-feature GEMM: x12 + al/ar (reads x f32 directly) ----------------
__global__ __launch_bounds__(256) void k_g0(const float* __restrict__ x,
                                            const ushort* __restrict__ wl12t,
                                            ushort* __restrict__ x12,   // [N][256]: (x1[c],x2[c]) f16 pairs
                                            float* __restrict__ alr,
                                            float* __restrict__ arr) {
    int tid = threadIdx.x;
    int w = tid >> 6, lane = tid & 63;
    int lrow = lane & 15, kg = lane >> 4;
    int cg = w & 1, rh = w >> 1;

    bf16x8 B[9][4];
#pragma unroll
    for (int c = 0; c < 9; ++c) {
        int ct = cg * 9 + c;
#pragma unroll
        for (int ks = 0; ks < 4; ++ks)
            B[c][ks] = *(const bf16x8*)(wl12t + (size_t)(ct * 16 + lrow) * 128 + ks * 32 + kg * 8);
    }

    for (int tile = blockIdx.x * 2 + rh; tile < NT_; tile += gridDim.x * 2) {
        int r0 = tile * 16;
        const float* Ap = x + (size_t)(r0 + lrow) * 128 + kg * 8;
        bf16x8 af[4];
#pragma unroll
        for (int ks = 0; ks < 4; ++ks) {
            float4 qa = *(const float4*)(Ap + ks * 32);
            float4 qb = *(const float4*)(Ap + ks * 32 + 4);
            bf16x8 t;
            t[0] = (short)f2bf(qa.x); t[1] = (short)f2bf(qa.y);
            t[2] = (short)f2bf(qa.z); t[3] = (short)f2bf(qa.w);
            t[4] = (short)f2bf(qb.x); t[5] = (short)f2bf(qb.y);
            t[6] = (short)f2bf(qb.z); t[7] = (short)f2bf(qb.w);
            af[ks] = t;
        }
        f32x4 acc[9];
#pragma unroll
        for (int c = 0; c < 9; ++c) acc[c] = (f32x4){0.f, 0.f, 0.f, 0.f};
#pragma unroll
        for (int ks = 0; ks < 4; ++ks)
#pragma unroll
            for (int c = 0; c < 9; ++c)
                acc[c] = __builtin_amdgcn_mfma_f32_16x16x32_bf16(af[ks], B[c][ks], acc[c], 0, 0, 0);

#pragma unroll
        for (int c = 0; c < 8; ++c) {
            int col = c * 16 + lrow;
#pragma unroll
            for (int jj = 0; jj < 4; ++jj) {
                int r = r0 + kg * 4 + jj;
                x12[(size_t)r * 256 + col * 2 + cg] = f2h(acc[c][jj]);
            }
        }
#pragma unroll
        for (int jj = 0; jj < 4; ++jj) {
            int r = r0 + kg * 4 + jj;
            float v = acc[8][jj];
            if (lrow < 8) alr[((size_t)r * 8 + lrow) * 2 + cg] = v;
            else          arr[((size_t)r * 8 + (lrow - 8)) * 2 + cg] = v;
        }
    }
}

// ---------------- persistent out-proj GEMM + residual + fused RMSNorm ----------------
__global__ __launch_bounds__(256) void k_g1(const ushort* __restrict__ attn,   // [N][128] bf16
                                            const ushort* __restrict__ woutt,  // [128][128] bf16
                                            const float* __restrict__ b1,
                                            const float* __restrict__ b2,
                                            const float* __restrict__ res,     // x f32
                                            const float* __restrict__ scale,
                                            float* __restrict__ hbuf,          // f32 out
                                            ushort* __restrict__ hn) {         // bf16 normed out
    int tid = threadIdx.x;
    int w = tid >> 6, lane = tid & 63;
    int lrow = lane & 15, kg = lane >> 4;

    bf16x8 B[8][4];
#pragma unroll
    for (int c = 0; c < 8; ++c)
#pragma unroll
        for (int ks = 0; ks < 4; ++ks)
            B[c][ks] = *(const bf16x8*)(woutt + (size_t)(c * 16 + lrow) * 128 + ks * 32 + kg * 8);

    for (int tile = blockIdx.x * 4 + w; tile < NT_; tile += gridDim.x * 4) {
        int r0 = tile * 16;
        const ushort* Ap = attn + (size_t)(r0 + lrow) * 128 + kg * 8;
        bf16x8 af[4];
#pragma unroll
        for (int ks = 0; ks < 4; ++ks) af[ks] = *(const bf16x8*)(Ap + ks * 32);
        f32x4 acc[8];
#pragma unroll
        for (int c = 0; c < 8; ++c) acc[c] = (f32x4){0.f, 0.f, 0.f, 0.f};
#pragma unroll
        for (int ks = 0; ks < 4; ++ks)
#pragma unroll
            for (int c = 0; c < 8; ++c)
                acc[c] = __builtin_amdgcn_mfma_f32_16x16x32_bf16(af[ks], B[c][ks], acc[c], 0, 0, 0);

        float ssj[4] = {0.f, 0.f, 0.f, 0.f};
#pragma unroll
        for (int c = 0; c < 8; ++c) {
            int col = c * 16 + lrow;
            float bv = b1[col] + b2[col];
#pragma unroll
            for (int jj = 0; jj < 4; ++jj) {
                int r = r0 + kg * 4 + jj;
                float v = acc[c][jj] + bv + res[(size_t)r * HC_ + col];
                acc[c][jj] = v;
                ssj[jj] += v * v;
            }
        }
        float rn[4];
#pragma unroll
        for (int jj = 0; jj < 4; ++jj) {
            float ss = ssj[jj];
            ss += __shfl_xor(ss, 1); ss += __shfl_xor(ss, 2);
            ss += __shfl_xor(ss, 4); ss += __shfl_xor(ss, 8);
            rn[jj] = rsqrtf(ss * (1.0f / 128.0f) + EPS_);
        }
#pragma unroll
        for (int c = 0; c < 8; ++c) {
            int col = c * 16 + lrow;
            float sc = scale[col];
#pragma unroll
            for (int jj = 0; jj < 4; ++jj) {
                int r = r0 + kg * 4 + jj;
                float v = acc[c][jj];
                hbuf[(size_t)r * HC_ + col] = v;
                hn[(size_t)r * HC_ + col] = f2bf(v * rn[jj] * sc);
            }
        }
    }
}

// ---------------- persistent ff1: g = gelu(hn @ Wff1 + b1), f16 out ----------------
__global__ __launch_bounds__(256) void k_ff1(const ushort* __restrict__ hn,     // [N][128] bf16
                                             const ushort* __restrict__ wff1t,  // [512][128] bf16
                                             const float* __restrict__ bff1,
                                             ushort* __restrict__ g) {          // [N][512] f16
    int tid = threadIdx.x;
    int w = tid >> 6, lane = tid & 63;
    int lrow = lane & 15, kg = lane >> 4;

    bf16x8 B[8][4];
#pragma unroll
    for (int c = 0; c < 8; ++c)
#pragma unroll
        for (int ks = 0; ks < 4; ++ks)
            B[c][ks] = *(const bf16x8*)(wff1t + (size_t)(w * 128 + c * 16 + lrow) * 128 + ks * 32 + kg * 8);

    for (int tile = blockIdx.x; tile < NT_; tile += gridDim.x) {
        int r0 = tile * 16;
        const ushort* Ap = hn + (size_t)(r0 + lrow) * 128 + kg * 8;
        bf16x8 af[4];
#pragma unroll
        for (int ks = 0; ks < 4; ++ks) af[ks] = *(const bf16x8*)(Ap + ks * 32);
        f32x4 acc[8];
#pragma unroll
        for (int c = 0; c < 8; ++c) acc[c] = (f32x4){0.f, 0.f, 0.f, 0.f};
#pragma unroll
        for (int ks = 0; ks < 4; ++ks)
#pragma unroll
            for (int c = 0; c < 8; ++c)
                acc[c] = __builtin_amdgcn_mfma_f32_16x16x32_bf16(af[ks], B[c][ks], acc[c], 0, 0, 0);

#pragma unroll
        for (int c = 0; c < 8; ++c) {
            int col = w * 128 + c * 16 + lrow;
            float bv = bff1[col];
#pragma unroll
            for (int jj = 0; jj < 4; ++jj) {
                float v = gelu_exact(acc[c][jj] + bv);
                float other = __shfl_xor(v, 1);
                if (!(lrow & 1)) {
                    int r = r0 + kg * 4 + jj;
                    ((uint*)g)[(size_t)r * 256 + (col >> 1)] = pkh2(v, other);
                }
            }
        }
    }
}

// ---------------- persistent ff2: out = h + g @ Wff2 + b2 (f16 MFMA, K=512) ----------------
__global__ __launch_bounds__(256) void k_ff2(const ushort* __restrict__ g,      // [N][512] f16
                                             const ushort* __restrict__ wff2t,  // [128][512] f16
                                             const float* __restrict__ bff2,
                                             const float* __restrict__ hres,    // f32
                                             float* __restrict__ out) {
    int tid = threadIdx.x;
    int w = tid >> 6, lane = tid & 63;
    int lrow = lane & 15, kg = lane >> 4;

    bf16x8 B[2][16];
#pragma unroll
    for (int c = 0; c < 2; ++c)
#pragma unroll
        for (int ks = 0; ks < 16; ++ks)
            B[c][ks] = *(const bf16x8*)(wff2t + (size_t)((2 * w + c) * 16 + lrow) * 512 + ks * 32 + kg * 8);

    for (int tile = blockIdx.x; tile < NT_; tile += gridDim.x) {
        int r0 = tile * 16;
        const ushort* Ap = g + (size_t)(r0 + lrow) * 512 + kg * 8;
        f32x4 acc[2];
        acc[0] = (f32x4){0.f, 0.f, 0.f, 0.f};
        acc[1] = (f32x4){0.f, 0.f, 0.f, 0.f};
#pragma unroll
        for (int ks = 0; ks < 16; ++ks) {
            bf16x8 af = *(const bf16x8*)(Ap + ks * 32);
            acc[0] = __builtin_amdgcn_mfma_f32_16x16x32_f16(af, B[0][ks], acc[0], 0, 0, 0);
            acc[1] = __builtin_amdgcn_mfma_f32_16x16x32_f16(af, B[1][ks], acc[1], 0, 0, 0);
        }
#pragma unroll
        for (int c = 0; c < 2; ++c) {
            int col = (2 * w + c) * 16 + lrow;
            float bv = bff2[col];
#pragma unroll
            for (int jj = 0; jj < 4; ++jj) {
                int r = r0 + kg * 4 + jj;
                out[(size_t)r * HC_ + col] = acc[c][jj] + bv + hres[(size_t)r * HC_ + col];
            }
        }
    }
}

extern "C" void kernel_launch(void* const* d_in, const int* in_sizes, int n_in,
                              void* d_out, int out_size, void* d_ws, size_t ws_size,
                              hipStream_t stream) {
    const float* x        = (const float*)d_in[0];
    const float* eattr    = (const float*)d_in[1];
    const float* W_l1     = (const float*)d_in[2];
    const float* W_l2     = (const float*)d_in[3];
    const float* att_l1   = (const float*)d_in[4];
    const float* att_r1   = (const float*)d_in[5];
    const float* att_l2   = (const float*)d_in[6];
    const float* att_r2   = (const float*)d_in[7];
    const float* W_e1     = (const float*)d_in[8];
    const float* att_e1   = (const float*)d_in[9];
    const float* W_e2     = (const float*)d_in[10];
    const float* att_e2   = (const float*)d_in[11];
    const float* lq1      = (const float*)d_in[12];
    const float* lk1      = (const float*)d_in[13];
    const float* lq2      = (const float*)d_in[14];
    const float* lk2      = (const float*)d_in[15];
    const float* rms_attn = (const float*)d_in[16];
    const float* W_out    = (const float*)d_in[17];
    const float* b_out    = (const float*)d_in[18];
    const float* bias_x   = (const float*)d_in[19];
    const float* rms_layer= (const float*)d_in[20];
    const float* W_ff1    = (const float*)d_in[21];
    const float* b_ff1    = (const float*)d_in[22];
    const float* W_ff2    = (const float*)d_in[23];
    const float* b_ff2    = (const float*)d_in[24];
    const int*   eidx     = (const int*)d_in[25];
    const int* src0 = eidx;
    const int* dst0 = eidx + E_;
    float* out = (float*)d_out;

    // ---- workspace layout ----
    char* base = (char*)d_ws;
    size_t off = 0;
    auto alloc = [&](size_t bytes) -> char* {
        off = (off + 255) & ~(size_t)255;
        char* p = base + off;
        off += bytes;
        return p;
    };
    const size_t NF = (size_t)N_ * HC_;
    float*  f_h    = (float*)alloc(NF * 4);
    ushort* f_hnat = (ushort*)alloc(NF * 2);        // attn bf16 then hn bf16
    ushort* f_x12  = (ushort*)alloc(NF * 2 * 2);    // interleaved f16 x1/x2 [N][256]
    char*   f_rg   = alloc((size_t)E_ * 64);        // rec (64B/edge, CSR) then g [N][512] f16
    uint*   f_rec  = (uint*)f_rg;
    ushort* f_g    = (ushort*)f_rg;
    ushort* w_l12t = (ushort*)alloc((size_t)288 * 128 * 2);
    ushort* w_outt = (ushort*)alloc((size_t)HC_ * HC_ * 2);
    ushort* w_ff1t = (ushort*)alloc((size_t)HC_ * FF_ * 2);
    ushort* w_ff2t = (ushort*)alloc((size_t)FF_ * HC_ * 2);
    float2* f_all  = (float2*)alloc((size_t)N_ * H_ * 8);
    float2* f_arr  = (float2*)alloc((size_t)N_ * H_ * 8);
    float2* f_wc   = (float2*)alloc(128 * 8);
    float*  f_lam  = (float*)alloc(256);
    int*  i_deg  = (int*)alloc((size_t)N_ * 4);
    int*  i_offs = (int*)alloc((size_t)(N_ + 1) * 4);
    int*  i_rank = (int*)alloc((size_t)E_ * 4);
    int*  i_csr  = (int*)alloc((size_t)E_ * 4);
    int2* i_de   = (int2*)alloc((size_t)E_ * 8);
    int*  i_perm = (int*)alloc((size_t)N_ * 4);
    int*  i_bkt  = (int*)alloc(64 * 4);
    (void)ws_size;

    hipMemsetAsync(i_deg, 0, (size_t)N_ * 4, stream);

    // ---- conversions + wc + lambda + degree histogram/rank ----
    k_cvt<<<dim3((CVT_TOTAL_ + 255) / 256), dim3(256), 0, stream>>>(
        W_l1, att_l1, att_r1, W_l2, att_l2, att_r2, W_out, W_ff1, W_ff2,
        W_e1, att_e1, W_e2, att_e2, lq1, lk1, lq2, lk2, dst0,
        w_l12t, w_outt, w_ff1t, w_ff2t, f_wc, f_lam, i_deg, i_rank);

    // ---- offsets + degree buckets; node permutation; CSR fill ----
    k_scan<<<dim3(1), dim3(1024), 0, stream>>>(i_deg, i_offs, i_bkt);
    k_perm<<<dim3((N_ + 255) / 256), dim3(256), 0, stream>>>(i_deg, i_bkt, i_perm);
    k_fill<<<dim3((E_ + 255) / 256), dim3(256), 0, stream>>>(src0, dst0, i_offs, i_rank,
                                                             i_csr, i_de);

    // ---- persistent node-feature GEMM (reads x f32 directly) ----
    k_g0<<<dim3(512), dim3(256), 0, stream>>>(x, w_l12t, f_x12,
                                              (float*)f_all, (float*)f_arr);

    // ---- per-edge records (p precomputed), CSR order ----
    k_et<<<dim3(E_ / 256), dim3(256), 0, stream>>>(eattr, f_all, f_arr, f_wc,
                                                   i_csr, i_de, f_rec);

    // ---- fused dual attention + combine + rmsnorm (degree-bucketed) ----
    k_agg<<<dim3((N_ + 3) / 4), dim3(256), 0, stream>>>(
        f_x12, f_all, f_arr, f_rec, f_wc,
        W_e1, W_e2, f_lam, rms_attn, i_offs, i_csr, i_perm, f_hnat);

    // ---- persistent out-proj + residual + RMSNorm ----
    k_g1<<<dim3(256), dim3(256), 0, stream>>>(f_hnat, w_outt, b_out, bias_x, x,
                                              rms_layer, f_h, f_hnat);

    // ---- persistent FFN (g aliases dead rec) ----
    k_ff1<<<dim3(512), dim3(256), 0, stream>>>(f_hnat, w_ff1t, b_ff1, f_g);
    k_ff2<<<dim3(1024), dim3(256), 0, stream>>>(f_g, w_ff2t, b_ff2, f_h, out);
}

// Round 18
// 438.139 us; speedup vs baseline: 1.3395x; 1.3395x over previous
//
#include <hip/hip_runtime.h>
#include <math.h>

// Problem constants
constexpr int N_  = 50000;
constexpr int E_  = 800000;
constexpr int H_  = 8;
constexpr int C_  = 16;
constexpr int HC_ = 128;
constexpr int ED_ = 16;        // E_DIM
constexpr int FF_ = 512;
constexpr int NT_ = 3125;      // row tiles of 16 (50000 = 16*3125 exact)
constexpr float NEG_ = 0.2f;
constexpr float EPS_ = 1e-5f;
constexpr float LAMBDA_INIT_ = 0.8f;
constexpr float LOG2E_ = 1.4426950408889634f;

typedef __attribute__((ext_vector_type(8))) short bf16x8;
typedef __attribute__((ext_vector_type(4))) float f32x4;
typedef __fp16 half2v __attribute__((ext_vector_type(2)));

__device__ __forceinline__ float gelu_exact(float v) {
    return 0.5f * v * (1.0f + erff(v * 0.70710678118654752440f));
}
__device__ __forceinline__ ushort f2bf(float f) {  // RNE f32 -> bf16
    uint u = __float_as_uint(f);
    return (ushort)((u + 0x7FFFu + ((u >> 16) & 1u)) >> 16);
}
__device__ __forceinline__ ushort f2h(float f) {   // f32 -> f16 bits (RNE)
    __fp16 h = (__fp16)f;
    return *(ushort*)&h;
}
__device__ __forceinline__ uint pkh2(float a, float b) {  // 2xf32 -> packed f16x2
    half2v h = __builtin_amdgcn_cvt_pkrtz(a, b);
    return *(uint*)&h;
}
__device__ __forceinline__ void uph2(uint u, float& a, float& b) {
    half2v h = *(half2v*)&u;
    a = (float)h.x; b = (float)h.y;
}

// ---------------- consolidated conversion kernel (+ degree histogram) ----------------
constexpr int WL12_ = 288 * 128;
constexpr int WO_   = 128 * 128;
constexpr int WF1_  = 512 * 128;
constexpr int WF2_  = 128 * 512;
constexpr int CVT_TOTAL_ = WL12_ + WO_ + WF1_ + WF2_ + 128 + 8 + E_;

__device__ void wconv(const float* __restrict__ W, ushort* __restrict__ Wt, int t, int K, int N) {
    int col = t / K, k = t - col * K;
    Wt[t] = f2bf(W[(size_t)k * N + col]);
}
__device__ void wconv_h(const float* __restrict__ W, ushort* __restrict__ Wt, int t, int K, int N) {
    int col = t / K, k = t - col * K;
    Wt[t] = f2h(W[(size_t)k * N + col]);
}

__global__ __launch_bounds__(256) void k_cvt(
        const float* __restrict__ Wl1, const float* __restrict__ al1w, const float* __restrict__ ar1w,
        const float* __restrict__ Wl2, const float* __restrict__ al2w, const float* __restrict__ ar2w,
        const float* __restrict__ Wout, const float* __restrict__ Wff1, const float* __restrict__ Wff2,
        const float* __restrict__ We1, const float* __restrict__ ae1,
        const float* __restrict__ We2, const float* __restrict__ ae2,
        const float* __restrict__ lq1, const float* __restrict__ lk1,
        const float* __restrict__ lq2, const float* __restrict__ lk2,
        const int* __restrict__ dst0,
        ushort* __restrict__ wl12t,
        ushort* __restrict__ woutt, ushort* __restrict__ wff1t, ushort* __restrict__ wff2t,
        float2* __restrict__ wc, float* __restrict__ lam,
        int* __restrict__ deg, int* __restrict__ rank) {
    int g = blockIdx.x * blockDim.x + threadIdx.x;
    if (g < WL12_) {
        int col = g >> 7, k = g & 127;
        const float* W = (col < 144) ? Wl1 : Wl2;
        const float* alw = (col < 144) ? al1w : al2w;
        const float* arw = (col < 144) ? ar1w : ar2w;
        int c = (col < 144) ? col : col - 144;
        float v;
        if (c < 128) {
            v = W[(size_t)k * HC_ + c];
        } else if (c < 136) {
            int h = c - 128; v = 0.f;
#pragma unroll
            for (int cc = 0; cc < 16; ++cc) v = fmaf(W[(size_t)k * HC_ + h * 16 + cc], alw[h * 16 + cc], v);
        } else {
            int h = c - 136; v = 0.f;
#pragma unroll
            for (int cc = 0; cc < 16; ++cc) v = fmaf(W[(size_t)k * HC_ + h * 16 + cc], arw[h * 16 + cc], v);
        }
        wl12t[g] = f2bf(v);
        return;
    }
    g -= WL12_;
    if (g < WO_) { wconv(Wout, woutt, g, 128, 128); return; }
    g -= WO_;
    if (g < WF1_) { wconv(Wff1, wff1t, g, 128, 512); return; }
    g -= WF1_;
    if (g < WF2_) { wconv_h(Wff2, wff2t, g, 512, 128); return; }
    g -= WF2_;
    if (g < 128) {
        int k = g >> 3, h = g & 7;
        float s1 = 0.f, s2 = 0.f;
#pragma unroll
        for (int c = 0; c < 16; ++c) {
            s1 = fmaf(We1[k * HC_ + h * 16 + c], ae1[h * 16 + c], s1);
            s2 = fmaf(We2[k * HC_ + h * 16 + c], ae2[h * 16 + c], s2);
        }
        wc[g] = make_float2(s1, s2);
        return;
    }
    g -= 128;
    if (g < 8) {
        float d1 = 0.f, d2 = 0.f;
#pragma unroll
        for (int k = 0; k < 16; ++k) {
            d1 = fmaf(lq1[g * 16 + k], lk1[g * 16 + k], d1);
            d2 = fmaf(lq2[g * 16 + k], lk2[g * 16 + k], d2);
        }
        lam[g] = __expf(d1) - __expf(d2) + LAMBDA_INIT_;
        return;
    }
    g -= 8;
    if (g < E_) {
        rank[g] = atomicAdd(&deg[dst0[g]], 1);
    }
}

// ---------------- exclusive scan of deg -> offsets ----------------
__global__ __launch_bounds__(1024) void k_scan(const int* __restrict__ deg,
                                               int* __restrict__ offs) {
    __shared__ int part[1024];
    int t = threadIdx.x;
    const int CH = (N_ + 1023) / 1024;  // 49
    int b = t * CH;
    int e = min(N_, b + CH);
    int sum = 0;
    for (int i = b; i < e; ++i) sum += deg[i];
    part[t] = sum;
    __syncthreads();
    for (int off = 1; off < 1024; off <<= 1) {
        int v = (t >= off) ? part[t - off] : 0;
        __syncthreads();
        part[t] += v;
        __syncthreads();
    }
    int run = (t == 0) ? 0 : part[t - 1];
    for (int i = b; i < e; ++i) {
        offs[i] = run;
        run += deg[i];
    }
    if (t == 1023) offs[N_] = run;  // == E_
}

// ---------------- CSR fill: 12B/edge scatter (src 4B + (dst,eid) 8B) ----------------
__global__ __launch_bounds__(256) void k_fill(const int* __restrict__ src0,
                                              const int* __restrict__ dst0,
                                              const int* __restrict__ offs,
                                              const int* __restrict__ rank,
                                              int* __restrict__ csr_src,
                                              int2* __restrict__ csr_de) {
    int e = blockIdx.x * blockDim.x + threadIdx.x;
    if (e >= E_) return;
    int d = dst0[e];
    int p = offs[d] + rank[e];
    csr_src[p] = src0[e];
    csr_de[p] = make_int2(d, e);
}

// ---------------- per-edge record builder, CSR order (sequential writes) ----------------
// thread p: rec[p] (64B seq) = [8 x half2(p1,p2) | 8 x half2(ea)], p = exp2(leaky(alpha)*log2e).
__global__ __launch_bounds__(256) void k_et(const float* __restrict__ eattr,
                                            const float2* __restrict__ all_,
                                            const float2* __restrict__ arr_,
                                            const float2* __restrict__ wc,
                                            const int* __restrict__ csr_src,
                                            const int2* __restrict__ csr_de,
                                            uint* __restrict__ rec) {
    __shared__ float2 wcs[128];
    int t = threadIdx.x;
    if (t < 128) wcs[t] = wc[t];
    __syncthreads();
    int p = blockIdx.x * blockDim.x + t;
    if (p >= E_) return;
    int2 de = csr_de[p];
    int dst = de.x, eid = de.y;
    int src = csr_src[p];
    const float* ea = eattr + (size_t)eid * ED_;
    float eav[16];
    {
        float4 q0 = *(const float4*)(ea + 0);
        float4 q1 = *(const float4*)(ea + 4);
        float4 q2 = *(const float4*)(ea + 8);
        float4 q3 = *(const float4*)(ea + 12);
        eav[0] = q0.x; eav[1] = q0.y; eav[2] = q0.z; eav[3] = q0.w;
        eav[4] = q1.x; eav[5] = q1.y; eav[6] = q1.z; eav[7] = q1.w;
        eav[8] = q2.x; eav[9] = q2.y; eav[10] = q2.z; eav[11] = q2.w;
        eav[12] = q3.x; eav[13] = q3.y; eav[14] = q3.z; eav[15] = q3.w;
    }
    const float2* alp = all_ + (size_t)dst * 8;
    const float2* arp = arr_ + (size_t)src * 8;
    uint ra[8], re[8];
#pragma unroll
    for (int h = 0; h < 8; ++h) {
        float t1 = 0.f, t2 = 0.f;
#pragma unroll
        for (int k = 0; k < 16; ++k) {
            float2 w = wcs[k * 8 + h];
            t1 = fmaf(eav[k], w.x, t1);
            t2 = fmaf(eav[k], w.y, t2);
        }
        float2 al = alp[h], ar = arp[h];
        float a1 = al.x + ar.x + t1;
        a1 = ((a1 >= 0.f) ? a1 : NEG_ * a1) * LOG2E_;
        float a2 = al.y + ar.y + t2;
        a2 = ((a2 >= 0.f) ? a2 : NEG_ * a2) * LOG2E_;
        ra[h] = pkh2(exp2f(a1), exp2f(a2));   // store p directly (max-free softmax)
    }
#pragma unroll
    for (int i = 0; i < 8; ++i) re[i] = pkh2(eav[2 * i], eav[2 * i + 1]);
    uint4* rp = (uint4*)(rec + (size_t)p * 16);
    rp[0] = make_uint4(ra[0], ra[1], ra[2], ra[3]);
    rp[1] = make_uint4(ra[4], ra[5], ra[6], ra[7]);
    rp[2] = make_uint4(re[0], re[1], re[2], re[3]);
    rp[3] = make_uint4(re[4], re[5], re[6], re[7]);
}

// ---------------- fused dual attention + diff combine + rmsnorm ----------------
// 4-edge batched loads for memory-level parallelism (latency-bound loop).
__global__ __launch_bounds__(256) void k_agg(const ushort* __restrict__ x12,
                                             const float2* __restrict__ all_,
                                             const float2* __restrict__ arr_,
                                             const uint* __restrict__ rec,
                                             const float2* __restrict__ wcg,
                                             const float* __restrict__ We1, const float* __restrict__ We2,
                                             const float* __restrict__ lam, const float* __restrict__ rms_attn,
                                             const int* __restrict__ offs, const int* __restrict__ csr_src,
                                             ushort* __restrict__ attn_out) {
    int wid = (int)((blockIdx.x * blockDim.x + threadIdx.x) >> 6);
    if (wid >= N_) return;
    int lane = threadIdx.x & 63;
    int h = lane >> 3;
    int cp = lane & 7;
    int e0 = h * C_ + cp * 2;
    int hbase = lane & 56;

    int s = offs[wid], eend = offs[wid + 1];
    int deg = eend - s;

    float s1 = 0.f, s2 = 0.f;
    float ax1x = 0.f, ax1y = 0.f, ax2x = 0.f, ax2y = 0.f;
    float ws1x = 0.f, ws1y = 0.f, ws2x = 0.f, ws2y = 0.f;
    float esx = 0.f, esy = 0.f;

    auto accum = [&](uint ua, uint ue, uint2 ux) {
        float p1, p2, eax, eay, x1a, x2a, x1b, x2b;
        uph2(ua, p1, p2);
        uph2(ue, eax, eay);
        uph2(ux.x, x1a, x2a);
        uph2(ux.y, x1b, x2b);
        s1 += p1; s2 += p2;
        ax1x = fmaf(p1, x1a, ax1x); ax1y = fmaf(p1, x1b, ax1y);
        ax2x = fmaf(p2, x2a, ax2x); ax2y = fmaf(p2, x2b, ax2y);
        ws1x = fmaf(p1, eax, ws1x); ws1y = fmaf(p1, eay, ws1y);
        ws2x = fmaf(p2, eax, ws2x); ws2y = fmaf(p2, eay, ws2y);
        esx += eax; esy += eay;
    };

    int j = s;
    // 4-edge batches: all loads issued before any use (12+ gathers in flight)
    for (; j + 3 < eend; j += 4) {
        int srcv[4];
#pragma unroll
        for (int q = 0; q < 4; ++q) srcv[q] = csr_src[j + q];
        uint uav[4], uev[4];
        uint2 uxv[4];
#pragma unroll
        for (int q = 0; q < 4; ++q) {
            const uint* r = rec + (size_t)(j + q) * 16;
            uav[q] = r[h];
            uev[q] = r[8 + cp];
            uxv[q] = *(const uint2*)(x12 + (size_t)srcv[q] * 256 + e0 * 2);
        }
#pragma unroll
        for (int q = 0; q < 4; ++q) accum(uav[q], uev[q], uxv[q]);
    }
    for (; j < eend; ++j) {
        int src = csr_src[j];
        const uint* r = rec + (size_t)j * 16;
        uint ua = r[h];
        uint ue = r[8 + cp];
        uint2 ux = *(const uint2*)(x12 + (size_t)src * 256 + e0 * 2);
        accum(ua, ue, ux);
    }

    // ---- self-loop: ea_self = mean of incoming ea ----
    float invdeg = 1.0f / (float)max(deg, 1);
    float esmx = esx * invdeg, esmy = esy * invdeg;

    float2 w0 = wcg[(2 * cp) * 8 + h];
    float2 w1 = wcg[(2 * cp + 1) * 8 + h];
    float tp1 = esmx * w0.x + esmy * w1.x;
    float tp2 = esmx * w0.y + esmy * w1.y;
    tp1 += __shfl_xor(tp1, 1); tp1 += __shfl_xor(tp1, 2); tp1 += __shfl_xor(tp1, 4);
    tp2 += __shfl_xor(tp2, 1); tp2 += __shfl_xor(tp2, 2); tp2 += __shfl_xor(tp2, 4);

    float2 alv = all_[(size_t)wid * 8 + h];
    float2 arv = arr_[(size_t)wid * 8 + h];
    float aS1 = alv.x + arv.x + tp1;
    aS1 = ((aS1 >= 0.f) ? aS1 : NEG_ * aS1) * LOG2E_;
    float aS2 = alv.y + arv.y + tp2;
    aS2 = ((aS2 >= 0.f) ? aS2 : NEG_ * aS2) * LOG2E_;
    float pS1 = exp2f(aS1), pS2 = exp2f(aS2);
    {
        uint2 ux = *(const uint2*)(x12 + (size_t)wid * 256 + e0 * 2);
        float x1a, x2a, x1b, x2b;
        uph2(ux.x, x1a, x2a);
        uph2(ux.y, x1b, x2b);
        s1 += pS1; s2 += pS2;
        ax1x = fmaf(pS1, x1a, ax1x); ax1y = fmaf(pS1, x1b, ax1y);
        ax2x = fmaf(pS2, x2a, ax2x); ax2y = fmaf(pS2, x2b, ax2y);
        ws1x = fmaf(pS1, esmx, ws1x); ws1y = fmaf(pS1, esmy, ws1y);
        ws2x = fmaf(pS2, esmx, ws2x); ws2y = fmaf(pS2, esmy, ws2y);
    }

    // ---- final: out = (ax + ws @ We) / s ----
    float o1x = ax1x, o1y = ax1y, o2x = ax2x, o2y = ax2y;
#pragma unroll
    for (int kp = 0; kp < 8; ++kp) {
        float wa1 = __shfl(ws1x, hbase + kp), wb1 = __shfl(ws1y, hbase + kp);
        float wa2 = __shfl(ws2x, hbase + kp), wb2 = __shfl(ws2y, hbase + kp);
        float2 a0 = *(const float2*)(We1 + (2 * kp) * HC_ + e0);
        float2 a1 = *(const float2*)(We1 + (2 * kp + 1) * HC_ + e0);
        float2 b0 = *(const float2*)(We2 + (2 * kp) * HC_ + e0);
        float2 b1 = *(const float2*)(We2 + (2 * kp + 1) * HC_ + e0);
        o1x = fmaf(wa1, a0.x, o1x); o1x = fmaf(wb1, a1.x, o1x);
        o1y = fmaf(wa1, a0.y, o1y); o1y = fmaf(wb1, a1.y, o1y);
        o2x = fmaf(wa2, b0.x, o2x); o2x = fmaf(wb2, b1.x, o2x);
        o2y = fmaf(wa2, b0.y, o2y); o2y = fmaf(wb2, b1.y, o2y);
    }
    float inv1 = 1.0f / s1, inv2 = 1.0f / s2;
    o1x *= inv1; o1y *= inv1; o2x *= inv2; o2y *= inv2;

    float lamh = lam[h];
    float v0 = o1x - lamh * o2x;
    float v1 = o1y - lamh * o2y;

    float ss = v0 * v0 + v1 * v1;
#pragma unroll
    for (int mk = 1; mk < 64; mk <<= 1) ss += __shfl_xor(ss, mk);
    float rn = rsqrtf(ss * (1.0f / 128.0f) + EPS_);
    float g0 = rms_attn[e0] * (1.0f - LAMBDA_INIT_);
    float g1 = rms_attn[e0 + 1] * (1.0f - LAMBDA_INIT_);
    ushort2 o;
    o.x = f2bf(v0 * rn * g0);
    o.y = f2bf(v1 * rn * g1);
    *(ushort2*)(attn_out + (size_t)wid * HC_ + e0) = o;
}

// ---------------- persistent node-feature GEMM: x12 + al/ar (reads x f32 directly) ----------------
__global__ __launch_bounds__(256) void k_g0(const float* __restrict__ x,
                                            const ushort* __restrict__ wl12t,
                                            ushort* __restrict__ x12,   // [N][256]: (x1[c],x2[c]) f16 pairs
                                            float* __restrict__ alr,
                                            float* __restrict__ arr) {
    int tid = threadIdx.x;
    int w = tid >> 6, lane = tid & 63;
    int lrow = lane & 15, kg = lane >> 4;
    int cg = w & 1, rh = w >> 1;

    bf16x8 B[9][4];
#pragma unroll
    for (int c = 0; c < 9; ++c) {
        int ct = cg * 9 + c;
#pragma unroll
        for (int ks = 0; ks < 4; ++ks)
            B[c][ks] = *(const bf16x8*)(wl12t + (size_t)(ct * 16 + lrow) * 128 + ks * 32 + kg * 8);
    }

    for (int tile = blockIdx.x * 2 + rh; tile < NT_; tile += gridDim.x * 2) {
        int r0 = tile * 16;
        const float* Ap = x + (size_t)(r0 + lrow) * 128 + kg * 8;
        bf16x8 af[4];
#pragma unroll
        for (int ks = 0; ks < 4; ++ks) {
            float4 qa = *(const float4*)(Ap + ks * 32);
            float4 qb = *(const float4*)(Ap + ks * 32 + 4);
            bf16x8 t;
            t[0] = (short)f2bf(qa.x); t[1] = (short)f2bf(qa.y);
            t[2] = (short)f2bf(qa.z); t[3] = (short)f2bf(qa.w);
            t[4] = (short)f2bf(qb.x); t[5] = (short)f2bf(qb.y);
            t[6] = (short)f2bf(qb.z); t[7] = (short)f2bf(qb.w);
            af[ks] = t;
        }
        f32x4 acc[9];
#pragma unroll
        for (int c = 0; c < 9; ++c) acc[c] = (f32x4){0.f, 0.f, 0.f, 0.f};
#pragma unroll
        for (int ks = 0; ks < 4; ++ks)
#pragma unroll
            for (int c = 0; c < 9; ++c)
                acc[c] = __builtin_amdgcn_mfma_f32_16x16x32_bf16(af[ks], B[c][ks], acc[c], 0, 0, 0);

#pragma unroll
        for (int c = 0; c < 8; ++c) {
            int col = c * 16 + lrow;
#pragma unroll
            for (int jj = 0; jj < 4; ++jj) {
                int r = r0 + kg * 4 + jj;
                x12[(size_t)r * 256 + col * 2 + cg] = f2h(acc[c][jj]);
            }
        }
#pragma unroll
        for (int jj = 0; jj < 4; ++jj) {
            int r = r0 + kg * 4 + jj;
            float v = acc[8][jj];
            if (lrow < 8) alr[((size_t)r * 8 + lrow) * 2 + cg] = v;
            else          arr[((size_t)r * 8 + (lrow - 8)) * 2 + cg] = v;
        }
    }
}

// ---------------- persistent out-proj GEMM + residual + fused RMSNorm ----------------
__global__ __launch_bounds__(256) void k_g1(const ushort* __restrict__ attn,   // [N][128] bf16
                                            const ushort* __restrict__ woutt,  // [128][128] bf16
                                            const float* __restrict__ b1,
                                            const float* __restrict__ b2,
                                            const float* __restrict__ res,     // x f32
                                            const float* __restrict__ scale,
                                            float* __restrict__ hbuf,          // f32 out
                                            ushort* __restrict__ hn) {         // bf16 normed out
    int tid = threadIdx.x;
    int w = tid >> 6, lane = tid & 63;
    int lrow = lane & 15, kg = lane >> 4;

    bf16x8 B[8][4];
#pragma unroll
    for (int c = 0; c < 8; ++c)
#pragma unroll
        for (int ks = 0; ks < 4; ++ks)
            B[c][ks] = *(const bf16x8*)(woutt + (size_t)(c * 16 + lrow) * 128 + ks * 32 + kg * 8);

    for (int tile = blockIdx.x * 4 + w; tile < NT_; tile += gridDim.x * 4) {
        int r0 = tile * 16;
        const ushort* Ap = attn + (size_t)(r0 + lrow) * 128 + kg * 8;
        bf16x8 af[4];
#pragma unroll
        for (int ks = 0; ks < 4; ++ks) af[ks] = *(const bf16x8*)(Ap + ks * 32);
        f32x4 acc[8];
#pragma unroll
        for (int c = 0; c < 8; ++c) acc[c] = (f32x4){0.f, 0.f, 0.f, 0.f};
#pragma unroll
        for (int ks = 0; ks < 4; ++ks)
#pragma unroll
            for (int c = 0; c < 8; ++c)
                acc[c] = __builtin_amdgcn_mfma_f32_16x16x32_bf16(af[ks], B[c][ks], acc[c], 0, 0, 0);

        float ssj[4] = {0.f, 0.f, 0.f, 0.f};
#pragma unroll
        for (int c = 0; c < 8; ++c) {
            int col = c * 16 + lrow;
            float bv = b1[col] + b2[col];
#pragma unroll
            for (int jj = 0; jj < 4; ++jj) {
                int r = r0 + kg * 4 + jj;
                float v = acc[c][jj] + bv + res[(size_t)r * HC_ + col];
                acc[c][jj] = v;
                ssj[jj] += v * v;
            }
        }
        float rn[4];
#pragma unroll
        for (int jj = 0; jj < 4; ++jj) {
            float ss = ssj[jj];
            ss += __shfl_xor(ss, 1); ss += __shfl_xor(ss, 2);
            ss += __shfl_xor(ss, 4); ss += __shfl_xor(ss, 8);
            rn[jj] = rsqrtf(ss * (1.0f / 128.0f) + EPS_);
        }
#pragma unroll
        for (int c = 0; c < 8; ++c) {
            int col = c * 16 + lrow;
            float sc = scale[col];
#pragma unroll
            for (int jj = 0; jj < 4; ++jj) {
                int r = r0 + kg * 4 + jj;
                float v = acc[c][jj];
                hbuf[(size_t)r * HC_ + col] = v;
                hn[(size_t)r * HC_ + col] = f2bf(v * rn[jj] * sc);
            }
        }
    }
}

// ---------------- persistent ff1: g = gelu(hn @ Wff1 + b1), f16 out ----------------
__global__ __launch_bounds__(256) void k_ff1(const ushort* __restrict__ hn,     // [N][128] bf16
                                             const ushort* __restrict__ wff1t,  // [512][128] bf16
                                             const float* __restrict__ bff1,
                                             ushort* __restrict__ g) {          // [N][512] f16
    int tid = threadIdx.x;
    int w = tid >> 6, lane = tid & 63;
    int lrow = lane & 15, kg = lane >> 4;

    bf16x8 B[8][4];
#pragma unroll
    for (int c = 0; c < 8; ++c)
#pragma unroll
        for (int ks = 0; ks < 4; ++ks)
            B[c][ks] = *(const bf16x8*)(wff1t + (size_t)(w * 128 + c * 16 + lrow) * 128 + ks * 32 + kg * 8);

    for (int tile = blockIdx.x; tile < NT_; tile += gridDim.x) {
        int r0 = tile * 16;
        const ushort* Ap = hn + (size_t)(r0 + lrow) * 128 + kg * 8;
        bf16x8 af[4];
#pragma unroll
        for (int ks = 0; ks < 4; ++ks) af[ks] = *(const bf16x8*)(Ap + ks * 32);
        f32x4 acc[8];
#pragma unroll
        for (int c = 0; c < 8; ++c) acc[c] = (f32x4){0.f, 0.f, 0.f, 0.f};
#pragma unroll
        for (int ks = 0; ks < 4; ++ks)
#pragma unroll
            for (int c = 0; c < 8; ++c)
                acc[c] = __builtin_amdgcn_mfma_f32_16x16x32_bf16(af[ks], B[c][ks], acc[c], 0, 0, 0);

#pragma unroll
        for (int c = 0; c < 8; ++c) {
            int col = w * 128 + c * 16 + lrow;
            float bv = bff1[col];
#pragma unroll
            for (int jj = 0; jj < 4; ++jj) {
                float v = gelu_exact(acc[c][jj] + bv);
                float other = __shfl_xor(v, 1);
                if (!(lrow & 1)) {
                    int r = r0 + kg * 4 + jj;
                    ((uint*)g)[(size_t)r * 256 + (col >> 1)] = pkh2(v, other);
                }
            }
        }
    }
}

// ---------------- persistent ff2: out = h + g @ Wff2 + b2 (f16 MFMA, K=512) ----------------
__global__ __launch_bounds__(256) void k_ff2(const ushort* __restrict__ g,      // [N][512] f16
                                             const ushort* __restrict__ wff2t,  // [128][512] f16
                                             const float* __restrict__ bff2,
                                             const float* __restrict__ hres,    // f32
                                             float* __restrict__ out) {
    int tid = threadIdx.x;
    int w = tid >> 6, lane = tid & 63;
    int lrow = lane & 15, kg = lane >> 4;

    bf16x8 B[2][16];
#pragma unroll
    for (int c = 0; c < 2; ++c)
#pragma unroll
        for (int ks = 0; ks < 16; ++ks)
            B[c][ks] = *(const bf16x8*)(wff2t + (size_t)((2 * w + c) * 16 + lrow) * 512 + ks * 32 + kg * 8);

    for (int tile = blockIdx.x; tile < NT_; tile += gridDim.x) {
        int r0 = tile * 16;
        const ushort* Ap = g + (size_t)(r0 + lrow) * 512 + kg * 8;
        f32x4 acc[2];
        acc[0] = (f32x4){0.f, 0.f, 0.f, 0.f};
        acc[1] = (f32x4){0.f, 0.f, 0.f, 0.f};
#pragma unroll
        for (int ks = 0; ks < 16; ++ks) {
            bf16x8 af = *(const bf16x8*)(Ap + ks * 32);
            acc[0] = __builtin_amdgcn_mfma_f32_16x16x32_f16(af, B[0][ks], acc[0], 0, 0, 0);
            acc[1] = __builtin_amdgcn_mfma_f32_16x16x32_f16(af, B[1][ks], acc[1], 0, 0, 0);
        }
#pragma unroll
        for (int c = 0; c < 2; ++c) {
            int col = (2 * w + c) * 16 + lrow;
            float bv = bff2[col];
#pragma unroll
            for (int jj = 0; jj < 4; ++jj) {
                int r = r0 + kg * 4 + jj;
                out[(size_t)r * HC_ + col] = acc[c][jj] + bv + hres[(size_t)r * HC_ + col];
            }
        }
    }
}

extern "C" void kernel_launch(void* const* d_in, const int* in_sizes, int n_in,
                              void* d_out, int out_size, void* d_ws, size_t ws_size,
                              hipStream_t stream) {
    const float* x        = (const float*)d_in[0];
    const float* eattr    = (const float*)d_in[1];
    const float* W_l1     = (const float*)d_in[2];
    const float* W_l2     = (const float*)d_in[3];
    const float* att_l1   = (const float*)d_in[4];
    const float* att_r1   = (const float*)d_in[5];
    const float* att_l2   = (const float*)d_in[6];
    const float* att_r2   = (const float*)d_in[7];
    const float* W_e1     = (const float*)d_in[8];
    const float* att_e1   = (const float*)d_in[9];
    const float* W_e2     = (const float*)d_in[10];
    const float* att_e2   = (const float*)d_in[11];
    const float* lq1      = (const float*)d_in[12];
    const float* lk1      = (const float*)d_in[13];
    const float* lq2      = (const float*)d_in[14];
    const float* lk2      = (const float*)d_in[15];
    const float* rms_attn = (const float*)d_in[16];
    const float* W_out    = (const float*)d_in[17];
    const float* b_out    = (const float*)d_in[18];
    const float* bias_x   = (const float*)d_in[19];
    const float* rms_layer= (const float*)d_in[20];
    const float* W_ff1    = (const float*)d_in[21];
    const float* b_ff1    = (const float*)d_in[22];
    const float* W_ff2    = (const float*)d_in[23];
    const float* b_ff2    = (const float*)d_in[24];
    const int*   eidx     = (const int*)d_in[25];
    const int* src0 = eidx;
    const int* dst0 = eidx + E_;
    float* out = (float*)d_out;

    // ---- workspace layout ----
    char* base = (char*)d_ws;
    size_t off = 0;
    auto alloc = [&](size_t bytes) -> char* {
        off = (off + 255) & ~(size_t)255;
        char* p = base + off;
        off += bytes;
        return p;
    };
    const size_t NF = (size_t)N_ * HC_;
    float*  f_h    = (float*)alloc(NF * 4);
    ushort* f_hnat = (ushort*)alloc(NF * 2);        // attn bf16 then hn bf16
    ushort* f_x12  = (ushort*)alloc(NF * 2 * 2);    // interleaved f16 x1/x2 [N][256]
    char*   f_rg   = alloc((size_t)E_ * 64);        // rec (64B/edge, CSR) then g [N][512] f16
    uint*   f_rec  = (uint*)f_rg;
    ushort* f_g    = (ushort*)f_rg;
    ushort* w_l12t = (ushort*)alloc((size_t)288 * 128 * 2);
    ushort* w_outt = (ushort*)alloc((size_t)HC_ * HC_ * 2);
    ushort* w_ff1t = (ushort*)alloc((size_t)HC_ * FF_ * 2);
    ushort* w_ff2t = (ushort*)alloc((size_t)FF_ * HC_ * 2);
    float2* f_all  = (float2*)alloc((size_t)N_ * H_ * 8);
    float2* f_arr  = (float2*)alloc((size_t)N_ * H_ * 8);
    float2* f_wc   = (float2*)alloc(128 * 8);
    float*  f_lam  = (float*)alloc(256);
    int*  i_deg  = (int*)alloc((size_t)N_ * 4);
    int*  i_offs = (int*)alloc((size_t)(N_ + 1) * 4);
    int*  i_rank = (int*)alloc((size_t)E_ * 4);
    int*  i_csr  = (int*)alloc((size_t)E_ * 4);
    int2* i_de   = (int2*)alloc((size_t)E_ * 8);
    (void)ws_size;

    hipMemsetAsync(i_deg, 0, (size_t)N_ * 4, stream);

    // ---- conversions + wc + lambda + degree histogram/rank ----
    k_cvt<<<dim3((CVT_TOTAL_ + 255) / 256), dim3(256), 0, stream>>>(
        W_l1, att_l1, att_r1, W_l2, att_l2, att_r2, W_out, W_ff1, W_ff2,
        W_e1, att_e1, W_e2, att_e2, lq1, lk1, lq2, lk2, dst0,
        w_l12t, w_outt, w_ff1t, w_ff2t, f_wc, f_lam, i_deg, i_rank);

    // ---- offsets, CSR fill ----
    k_scan<<<dim3(1), dim3(1024), 0, stream>>>(i_deg, i_offs);
    k_fill<<<dim3((E_ + 255) / 256), dim3(256), 0, stream>>>(src0, dst0, i_offs, i_rank,
                                                             i_csr, i_de);

    // ---- persistent node-feature GEMM (reads x f32 directly) ----
    k_g0<<<dim3(512), dim3(256), 0, stream>>>(x, w_l12t, f_x12,
                                              (float*)f_all, (float*)f_arr);

    // ---- per-edge records (p precomputed), CSR order ----
    k_et<<<dim3(E_ / 256), dim3(256), 0, stream>>>(eattr, f_all, f_arr, f_wc,
                                                   i_csr, i_de, f_rec);

    // ---- fused dual attention + combine + rmsnorm ----
    k_agg<<<dim3((N_ + 3) / 4), dim3(256), 0, stream>>>(
        f_x12, f_all, f_arr, f_rec, f_wc,
        W_e1, W_e2, f_lam, rms_attn, i_offs, i_csr, f_hnat);

    // ---- persistent out-proj + residual + RMSNorm ----
    k_g1<<<dim3(256), dim3(256), 0, stream>>>(f_hnat, w_outt, b_out, bias_x, x,
                                              rms_layer, f_h, f_hnat);

    // ---- persistent FFN (g aliases dead rec) ----
    k_ff1<<<dim3(512), dim3(256), 0, stream>>>(f_hnat, w_ff1t, b_ff1, f_g);
    k_ff2<<<dim3(1024), dim3(256), 0, stream>>>(f_g, w_ff2t, b_ff2, f_h, out);
}